// Round 9
// baseline (1371.561 us; speedup 1.0000x reference)
//
#include <hip/hip_runtime.h>
#include <math.h>

#define DIM 7168
#define NE 256
#define NG 8
#define GSZ 32
#define TOPG 4
#define TOPK_N 8
#define NKT 224          // DIM/32 k-tiles total
#define KSPLIT 8
#define KTS 28           // NKT/KSPLIT
#define KSLICE 896       // DIM/KSPLIT
#define BM 128

typedef short bf16x8 __attribute__((ext_vector_type(8)));
typedef float f32x4 __attribute__((ext_vector_type(4)));

#define DREL 4e-5

__device__ __forceinline__ unsigned short bf16_rne(float f) {
    unsigned u = __float_as_uint(f);
    unsigned r = u + 0x7FFFu + ((u >> 16) & 1u);
    return (unsigned short)(r >> 16);
}
__device__ __forceinline__ float bf16_to_f32(unsigned short h) {
    return __uint_as_float(((unsigned)h) << 16);
}

// ---------------- K0: repack W into fragment-major bf16 hi/lo ----------------
// frag id gid = (ct*NKT + kt)*64 + l ; element j: w[ct*16+(l&15)][kt*32+(l>>4)*8+j]
__global__ void k0_repack(const float* __restrict__ w,
                          unsigned short* __restrict__ wh,
                          unsigned short* __restrict__ wl) {
    const int gid = blockIdx.x * 256 + threadIdx.x;
    if (gid >= 16 * NKT * 64) return;
    const int l  = gid & 63;
    const int kt = (gid >> 6) % NKT;
    const int ct = gid / (NKT * 64);
    const int e  = ct * 16 + (l & 15);
    const int k0 = kt * 32 + (l >> 4) * 8;
    const float* src = w + (size_t)e * DIM + k0;
    float4 u0 = *(const float4*)src;
    float4 u1 = *(const float4*)(src + 4);
    const float uu[8] = {u0.x, u0.y, u0.z, u0.w, u1.x, u1.y, u1.z, u1.w};
    ushort4 ho[2], lo[2];
    unsigned short* hp = (unsigned short*)ho;
    unsigned short* lp = (unsigned short*)lo;
#pragma unroll
    for (int q = 0; q < 8; ++q) {
        unsigned short hb = bf16_rne(uu[q]);
        float hf = bf16_to_f32(hb);
        unsigned short lb = bf16_rne(uu[q] - hf);
        hp[q] = hb; lp[q] = lb;
    }
    *(ushort4*)(wh + (size_t)gid * 8)     = ho[0];
    *(ushort4*)(wh + (size_t)gid * 8 + 4) = ho[1];
    *(ushort4*)(wl + (size_t)gid * 8)     = lo[0];
    *(ushort4*)(wl + (size_t)gid * 8 + 4) = lo[1];
}

// ---------------- K1: XCD-pinned fragment GEMM (3-term split bf16) ----------------
// Work item = (rb, ks). Per-XCD queues: block reads its XCC_ID, drains its own
// queue (W k-slice stays in its L2), then steals. x staged via LDS dbuf.
__global__ __launch_bounds__(512, 4) void k1_gemm(
    const float* __restrict__ x,
    const unsigned short* __restrict__ wh, const unsigned short* __restrict__ wl,
    float* __restrict__ part, unsigned* __restrict__ ctrs, int n, int np, int nrb)
{
    __shared__ __align__(16) char smx[2][16384];   // x tile [128 rows][32 f32], dbuf
    __shared__ int s_rb;
    const int t  = threadIdx.x;
    const int l  = t & 63;
    const int wv = t >> 6;
    const int rg = wv >> 2;          // row-group 0..1  (rt = rg*4 .. +3)
    const int cg = wv & 3;           // ct-group 0..3   (ct = cg*4 .. +3)
    const int kslot = l >> 4;
    const int ml = l & 15;
    const unsigned xcd = __builtin_amdgcn_s_getreg(63508) & 7u;  // HW_REG_XCC_ID

    const int r0s = t >> 3;          // staging row 0..63
    const int c4  = t & 7;           // staging 16B chunk within 128B row

    for (int dk = 0; dk < 8; ++dk) {
        const int ks = (int)((xcd + (unsigned)dk) & 7u);
        while (true) {
            __syncthreads();
            if (t == 0) s_rb = (int)atomicAdd(&ctrs[ks], 1u);
            __syncthreads();
            const int rb = s_rb;
            if (rb >= nrb) break;

            const int row0 = rb * BM;
            f32x4 acc[4][4];
#pragma unroll
            for (int a = 0; a < 4; ++a)
#pragma unroll
                for (int b = 0; b < 4; ++b) acc[a][b] = (f32x4){0.f, 0.f, 0.f, 0.f};

            int rowA = row0 + r0s;      if (rowA > n - 1) rowA = n - 1;
            int rowB = row0 + 64 + r0s; if (rowB > n - 1) rowB = n - 1;
            const size_t xb0 = (size_t)rowA * DIM + (size_t)ks * KSLICE + c4 * 4;
            const size_t xb1 = (size_t)rowB * DIM + (size_t)ks * KSLICE + c4 * 4;
            const int lo0 = r0s * 128 + c4 * 16;
            const int lo1 = (64 + r0s) * 128 + c4 * 16;
            float4 pa = *(const float4*)&x[xb0];
            float4 pb = *(const float4*)&x[xb1];

            for (int tt = 0; tt < KTS; ++tt) {
                char* buf = smx[tt & 1];
                *(float4*)(buf + lo0) = pa;
                *(float4*)(buf + lo1) = pb;
                const int tn = (tt + 1 < KTS) ? tt + 1 : tt;
                pa = *(const float4*)&x[xb0 + (size_t)tn * 32];
                pb = *(const float4*)&x[xb1 + (size_t)tn * 32];
                __syncthreads();

                const int kt = ks * KTS + tt;
                bf16x8 ah[4], al[4];
#pragma unroll
                for (int rtl = 0; rtl < 4; ++rtl) {
                    const int ra = (rg * 4 + rtl) * 16 + ml;
                    const char* px = buf + ra * 128 + kslot * 32;
                    const float4 u0 = *(const float4*)px;
                    const float4 u1 = *(const float4*)(px + 16);
                    const float uu[8] = {u0.x, u0.y, u0.z, u0.w, u1.x, u1.y, u1.z, u1.w};
                    bf16x8 hh, ll;
#pragma unroll
                    for (int q = 0; q < 8; ++q) {
                        const unsigned u  = __float_as_uint(uu[q]);
                        const unsigned hr = (u + 0x7FFFu + ((u >> 16) & 1u)) & 0xFFFF0000u;
                        const float lofv  = uu[q] - __uint_as_float(hr);
                        hh[q] = (short)(hr >> 16);
                        ll[q] = (short)(__float_as_uint(lofv) >> 16);   // lo truncated: residual ~2^-17
                    }
                    ah[rtl] = hh; al[rtl] = ll;
                }
#pragma unroll
                for (int ci = 0; ci < 4; ++ci) {
                    const int ct = cg * 4 + ci;
                    const size_t fb = ((size_t)(ct * NKT + kt) * 64 + l) * 8;
                    const bf16x8 bh = *(const bf16x8*)(wh + fb);
                    const bf16x8 bl = *(const bf16x8*)(wl + fb);
#pragma unroll
                    for (int rtl = 0; rtl < 4; ++rtl) {
                        acc[rtl][ci] = __builtin_amdgcn_mfma_f32_16x16x32_bf16(ah[rtl], bh, acc[rtl][ci], 0, 0, 0);
                        acc[rtl][ci] = __builtin_amdgcn_mfma_f32_16x16x32_bf16(ah[rtl], bl, acc[rtl][ci], 0, 0, 0);
                        acc[rtl][ci] = __builtin_amdgcn_mfma_f32_16x16x32_bf16(al[rtl], bh, acc[rtl][ci], 0, 0, 0);
                    }
                }
            }
            // D layout: col = lane&15 (expert), row = 4*(lane>>4)+j (verified r8)
            float* pp = part + (size_t)ks * np * NE;
#pragma unroll
            for (int rtl = 0; rtl < 4; ++rtl) {
                const int rbase = row0 + (rg * 4 + rtl) * 16 + 4 * kslot;
#pragma unroll
                for (int ci = 0; ci < 4; ++ci) {
                    const int e = (cg * 4 + ci) * 16 + ml;
#pragma unroll
                    for (int j = 0; j < 4; ++j)
                        pp[(size_t)(rbase + j) * NE + e] = acc[rtl][ci][j];
                }
            }
        }
    }
}

// ---------------- K1b: combine partials + certificate routing ----------------
__global__ __launch_bounds__(256) void k1b_route(
    const float* __restrict__ part, const float* __restrict__ bias,
    float* __restrict__ out, unsigned* __restrict__ counter,
    int* __restrict__ list, int n, int np, unsigned lcap)
{
    __shared__ float sc[32][NE + 2];
    const int t  = threadIdx.x;
    const int r0 = blockIdx.x * 32;
#pragma unroll 1
    for (int r = 0; r < 32; ++r) {
        const size_t off = (size_t)(r0 + r) * NE + t;
        float z = 0.f;
#pragma unroll
        for (int ks = 0; ks < KSPLIT; ++ks)
            z += part[(size_t)ks * np * NE + off];
        sc[r][t] = z;
    }
    __syncthreads();

    if (t < 32) {
        const int row = r0 + t;
        if (row < n) {
            float* srow = sc[t];
            float zmaxf = -3e38f;
            for (int e = 0; e < NE; ++e) zmaxf = fmaxf(zmaxf, srow[e]);
            double Z = 0.0;
            for (int e = 0; e < NE; ++e) {
                float p = __expf(srow[e] - zmaxf);
                srow[e] = p;
                Z += (double)p;
            }
            const double invZ = 1.0 / Z;

            bool flag = false;
            double gs[NG], dg[NG];
            for (int g = 0; g < NG; ++g) {
                double v1 = -1e300, v2 = -1e300, v3 = -1e300;
                double d1 = 0, d2 = 0, d3 = 0;
                for (int i = 0; i < GSZ; ++i) {
                    double p = (double)srow[g * GSZ + i] * invZ;
                    double v = p + (double)bias[g * GSZ + i];
                    double d = DREL * p;
                    if (v > v1)      { v3 = v2; d3 = d2; v2 = v1; d2 = d1; v1 = v; d1 = d; }
                    else if (v > v2) { v3 = v2; d3 = d2; v2 = v;  d2 = d; }
                    else if (v > v3) { v3 = v;  d3 = d; }
                }
                if (v2 - v3 <= d2 + d3) flag = true;
                gs[g] = v1 + v2; dg[g] = d1 + d2;
            }
            unsigned keep = 0;
            for (int tt = 0; tt < TOPG; ++tt) {
                double best = -1e300; int bg = 0;
                for (int g = 0; g < NG; ++g)
                    if (!((keep >> g) & 1u) && gs[g] > best) { best = gs[g]; bg = g; }
                keep |= 1u << bg;
            }
            {
                double mn = 1e300, mx = -1e300;
                for (int g = 0; g < NG; ++g) {
                    if ((keep >> g) & 1u) mn = fmin(mn, gs[g] - dg[g]);
                    else                  mx = fmax(mx, gs[g] + dg[g]);
                }
                if (mn <= mx) flag = true;
            }
            unsigned long long tk[4] = {0ull, 0ull, 0ull, 0ull};
            double pv[9], pd[9]; int pe[9];
            for (int pp = 0; pp < 9; ++pp) {
                double best = -1e300, bd = 0; int be = 0;
                for (int e = 0; e < NE; ++e) {
                    if (!((keep >> (e >> 5)) & 1u)) continue;
                    if ((tk[e >> 6] >> (e & 63)) & 1ull) continue;
                    double p = (double)srow[e] * invZ;
                    double s = p + (double)bias[e];
                    if (s > best) { best = s; bd = DREL * p; be = e; }
                }
                tk[be >> 6] |= 1ull << (be & 63);
                pv[pp] = best; pd[pp] = bd; pe[pp] = be;
            }
            for (int i = 0; i < 8; ++i)
                if (pv[i] - pv[i + 1] <= pd[i] + pd[i + 1]) flag = true;

            float* out_w = out;
            float* out_i = out + (size_t)n * TOPK_N;
            for (int pp = 0; pp < TOPK_N; ++pp) {
                out_w[(size_t)row * TOPK_N + pp] = (float)((double)srow[pe[pp]] * invZ * 2.5);
                out_i[(size_t)row * TOPK_N + pp] = (float)pe[pp];
            }
            if (flag) {
                unsigned idx = atomicAdd(counter, 1u);
                if (idx < lcap) list[idx] = row;
            }
        }
    }
}

// ---------------- K2: exact fp64 recompute, coalesced, 4 rows/block ----------------
__global__ __launch_bounds__(512) void k2_exact(
    const float* __restrict__ x, const float* __restrict__ w,
    const float* __restrict__ bias, float* __restrict__ out,
    const unsigned* __restrict__ counter, const int* __restrict__ list,
    int n, unsigned lcap)
{
    __shared__ __align__(16) char sm2[65536];
    float* xr = (float*)sm2;                                   // [4][3584] f32 (K half)
    double (*zp)[NE] = (double(*)[NE])(sm2 + 57344);           // [4][256] f64

    const unsigned F = min(*counter, lcap);
    const int base = blockIdx.x * 4;
    if ((unsigned)base >= F) return;
    const int t = threadIdx.x;
    int rows[4];
#pragma unroll
    for (int i = 0; i < 4; ++i) {
        int idx = base + i; if ((unsigned)idx >= F) idx = base;
        rows[i] = list[idx];
    }
    const int wv = t >> 6, l = t & 63;

    for (int h = 0; h < 2; ++h) {
        __syncthreads();   // previous half fully consumed
        // stage x half: 4 rows x 3584 f32, coalesced
        for (int it = 0; it < 7; ++it) {
            const int f = it * 512 + t;          // float4 index, 3584 total
            const int r = f / 896;
            const int c = f - r * 896;
            *(float4*)(xr + r * 3584 + c * 4) =
                *(const float4*)&x[(size_t)rows[r] * DIM + h * 3584 + c * 4];
        }
        __syncthreads();
        for (int pass = 0; pass < 8; ++pass) {
            const int e0 = (pass * 8 + wv) * 4;
            double a[4][4];
#pragma unroll
            for (int j = 0; j < 4; ++j)
#pragma unroll
                for (int r = 0; r < 4; ++r) a[j][r] = 0.0;
            for (int i = 0; i < 56; ++i) {
                const int k = i * 64 + l;        // local k within half
                double wd[4], xd[4];
#pragma unroll
                for (int j = 0; j < 4; ++j)
                    wd[j] = (double)w[(size_t)(e0 + j) * DIM + h * 3584 + k];
#pragma unroll
                for (int r = 0; r < 4; ++r) xd[r] = (double)xr[r * 3584 + k];
#pragma unroll
                for (int j = 0; j < 4; ++j)
#pragma unroll
                    for (int r = 0; r < 4; ++r)
                        a[j][r] = fma(wd[j], xd[r], a[j][r]);
            }
#pragma unroll
            for (int j = 0; j < 4; ++j)
#pragma unroll
                for (int r = 0; r < 4; ++r) {
                    double v = a[j][r];
#pragma unroll
                    for (int off = 32; off >= 1; off >>= 1)
                        v += __shfl_xor(v, off);
                    if (l == 0) {
                        if (h == 0) zp[r][e0 + j] = v;
                        else        zp[r][e0 + j] += v;
                    }
                }
        }
    }
    __syncthreads();

    if (t < 4 && (unsigned)(base + t) < F) {
        const int row = rows[t];
        double* srow = zp[t];
        double zmax = -1e300;
        for (int ee = 0; ee < NE; ++ee) zmax = fmax(zmax, srow[ee]);
        double Z = 0.0;
        for (int ee = 0; ee < NE; ++ee) {
            double p = exp(srow[ee] - zmax);
            srow[ee] = p;
            Z += p;
        }
        const double invZ = 1.0 / Z;
        double gs[NG];
        for (int g = 0; g < NG; ++g) {
            double m1 = -1e300, m2 = -1e300;
            for (int i = 0; i < GSZ; ++i) {
                double v = srow[g * GSZ + i] * invZ + (double)bias[g * GSZ + i];
                if (v > m1) { m2 = m1; m1 = v; }
                else if (v > m2) { m2 = v; }
            }
            gs[g] = m1 + m2;
        }
        unsigned keep = 0;
        for (int tt = 0; tt < TOPG; ++tt) {
            double best = -1e300; int bg = 0;
            for (int g = 0; g < NG; ++g)
                if (!((keep >> g) & 1u) && gs[g] > best) { best = gs[g]; bg = g; }
            keep |= 1u << bg;
        }
        unsigned long long tk[4] = {0ull, 0ull, 0ull, 0ull};
        float* out_w = out;
        float* out_i = out + (size_t)n * TOPK_N;
        for (int pp = 0; pp < TOPK_N; ++pp) {
            double best = -1e300; int be = 0;
            for (int ee = 0; ee < NE; ++ee) {
                if (!((keep >> (ee >> 5)) & 1u)) continue;
                if ((tk[ee >> 6] >> (ee & 63)) & 1ull) continue;
                double s = srow[ee] * invZ + (double)bias[ee];
                if (s > best) { best = s; be = ee; }
            }
            tk[be >> 6] |= 1ull << (be & 63);
            out_w[(size_t)row * TOPK_N + pp] = (float)(srow[be] * invZ * 2.5);
            out_i[(size_t)row * TOPK_N + pp] = (float)be;
        }
    }
}

// ---------------- fallback (proven r6 fp64 kernel) if ws too small ----------------
#define OBM 32
#define OBK 16
#define ONCH (DIM / OBK)
__global__ __launch_bounds__(512) void gate_kernel_old(
    const float* __restrict__ x, const float* __restrict__ w,
    const float* __restrict__ bias, float* __restrict__ out, int n)
{
    __shared__ __align__(16) char smem[65536];
    float  (*w2)[OBK][NE] = reinterpret_cast<float(*)[OBK][NE]>(smem);
    double (*x2)[OBK][34] = reinterpret_cast<double(*)[OBK][34]>(smem + 32768);
    double (*sc)[OBM]     = reinterpret_cast<double(*)[OBM]>(smem);
    const int t = threadIdx.x;
    const int row0 = blockIdx.x * OBM;
    const int we = t & 255;
    const int h8 = (t >> 8) * 8;
    const size_t wbase = (size_t)we * DIM + h8;
    const int rx = t >> 2;
    const int kx = (t & 3) * 4;
    int rr = row0 + rx; if (rr > n - 1) rr = n - 1;
    const size_t xbase = (size_t)rr * DIM + kx;
    const int wv = t >> 6, lane = t & 63;
    const int h = wv & 1, rg = wv >> 1, rb = 8 * rg;
    const int e0 = 128 * h + 2 * lane;
    double acc[8][2];
#pragma unroll
    for (int i = 0; i < 8; ++i) { acc[i][0] = 0.0; acc[i][1] = 0.0; }
    float4 wra = *(const float4*)&w[wbase];
    float4 wrb = *(const float4*)&w[wbase + 4];
    float4 xr = make_float4(0.f, 0.f, 0.f, 0.f);
    if (t < 128) xr = *(const float4*)&x[xbase];
    for (int c = 0; c < ONCH; ++c) {
        const int b = c & 1;
        const float* fa = (const float*)&wra;
        const float* fb = (const float*)&wrb;
#pragma unroll
        for (int q = 0; q < 4; ++q) {
            w2[b][h8 + q][we] = fa[q];
            w2[b][h8 + 4 + q][we] = fb[q];
        }
        if (t < 128) {
            const float* fx = (const float*)&xr;
#pragma unroll
            for (int q = 0; q < 4; ++q) x2[b][kx + q][rx] = (double)fx[q];
        }
        const size_t k0 = (size_t)((c + 1 < ONCH) ? c + 1 : c) * OBK;
        wra = *(const float4*)&w[wbase + k0];
        wrb = *(const float4*)&w[wbase + k0 + 4];
        if (t < 128) xr = *(const float4*)&x[xbase + k0];
        __syncthreads();
#pragma unroll
        for (int kk = 0; kk < OBK; ++kk) {
            const float2 wf = *(const float2*)&w2[b][kk][e0];
            const double wd0 = (double)wf.x, wd1 = (double)wf.y;
            const double2 xp0 = *(const double2*)&x2[b][kk][rb];
            const double2 xp1 = *(const double2*)&x2[b][kk][rb + 2];
            const double2 xp2 = *(const double2*)&x2[b][kk][rb + 4];
            const double2 xp3 = *(const double2*)&x2[b][kk][rb + 6];
            const double xv[8] = {xp0.x, xp0.y, xp1.x, xp1.y, xp2.x, xp2.y, xp3.x, xp3.y};
#pragma unroll
            for (int i = 0; i < 8; ++i) {
                acc[i][0] = fma(xv[i], wd0, acc[i][0]);
                acc[i][1] = fma(xv[i], wd1, acc[i][1]);
            }
        }
    }
    __syncthreads();
#pragma unroll
    for (int j = 0; j < 2; ++j)
#pragma unroll
        for (int q = 0; q < 4; ++q) {
            double2 v; v.x = acc[2 * q][j]; v.y = acc[2 * q + 1][j];
            *(double2*)&sc[e0 + j][rb + 2 * q] = v;
        }
    __syncthreads();
    if (t < OBM) {
        const int row = row0 + t;
        if (row < n) {
            double zmax = -1e300;
            for (int e = 0; e < NE; ++e) zmax = fmax(zmax, sc[e][t]);
            double Z = 0.0;
            for (int e = 0; e < NE; ++e) { double p = exp(sc[e][t] - zmax); sc[e][t] = p; Z += p; }
            const double invZ = 1.0 / Z;
            double gs[NG];
            for (int g = 0; g < NG; ++g) {
                double m1 = -1e300, m2 = -1e300;
                for (int i = 0; i < GSZ; ++i) {
                    double v = sc[g * GSZ + i][t] * invZ + (double)bias[g * GSZ + i];
                    if (v > m1) { m2 = m1; m1 = v; } else if (v > m2) m2 = v;
                }
                gs[g] = m1 + m2;
            }
            unsigned keep = 0;
            for (int tt = 0; tt < TOPG; ++tt) {
                double best = -1e300; int bg = 0;
                for (int g = 0; g < NG; ++g)
                    if (!((keep >> g) & 1u) && gs[g] > best) { best = gs[g]; bg = g; }
                keep |= 1u << bg;
            }
            unsigned long long tk[4] = {0ull, 0ull, 0ull, 0ull};
            float* out_w = out;
            float* out_i = out + (size_t)n * TOPK_N;
            for (int pp = 0; pp < TOPK_N; ++pp) {
                double best = -1e300; int be = 0;
                for (int e = 0; e < NE; ++e) {
                    if (!((keep >> (e >> 5)) & 1u)) continue;
                    if ((tk[e >> 6] >> (e & 63)) & 1ull) continue;
                    double s = sc[e][t] * invZ + (double)bias[e];
                    if (s > best) { best = s; be = e; }
                }
                tk[be >> 6] |= 1ull << (be & 63);
                out_w[(size_t)row * TOPK_N + pp] = (float)(sc[be][t] * invZ * 2.5);
                out_i[(size_t)row * TOPK_N + pp] = (float)be;
            }
        }
    }
}

extern "C" void kernel_launch(void* const* d_in, const int* in_sizes, int n_in,
                              void* d_out, int out_size, void* d_ws, size_t ws_size,
                              hipStream_t stream) {
    const float* x  = (const float*)d_in[0];
    const float* w  = (const float*)d_in[1];
    const float* b  = (const float*)d_in[2];
    float* out      = (float*)d_out;
    const int n     = in_sizes[0] / DIM;
    const int np    = (n + BM - 1) & ~(BM - 1);
    const int nrb   = np / BM;

    const size_t WBYTES   = (size_t)16 * NKT * 64 * 8 * 2;  // 3,670,016 per array
    const size_t off_list = 4096;
    const size_t off_wh   = off_list + (((size_t)np * 4 + 255) & ~(size_t)255);
    const size_t off_wl   = off_wh + WBYTES;
    const size_t off_part = off_wl + WBYTES;
    const size_t need     = off_part + (size_t)KSPLIT * np * NE * 4;

    if (ws_size < need) {
        gate_kernel_old<<<(n + OBM - 1) / OBM, 512, 0, stream>>>(x, w, b, out, n);
        return;
    }
    char* ws = (char*)d_ws;
    unsigned* xctrs     = (unsigned*)ws;            // 8 per-XCD work counters
    unsigned* flagctr   = (unsigned*)(ws + 32);     // flagged-row counter
    int* list           = (int*)(ws + off_list);
    unsigned short* wh  = (unsigned short*)(ws + off_wh);
    unsigned short* wl  = (unsigned short*)(ws + off_wl);
    float* part         = (float*)(ws + off_part);

    hipMemsetAsync(ws, 0, 64, stream);
    k0_repack<<<(16 * NKT * 64) / 256, 256, 0, stream>>>(w, wh, wl);
    k1_gemm<<<nrb * KSPLIT, 512, 0, stream>>>(x, wh, wl, part, xctrs, n, np, nrb);
    k1b_route<<<np / 32, 256, 0, stream>>>(part, b, out, flagctr, list, n, np, (unsigned)np);
    k2_exact<<<(n + 3) / 4, 512, 0, stream>>>(x, w, b, out, flagctr, list, n, (unsigned)np);
}

// Round 10
// 957.655 us; speedup vs baseline: 1.4322x; 1.4322x over previous
//
#include <hip/hip_runtime.h>
#include <math.h>

#define DIM 7168
#define NE 256
#define NG 8
#define GSZ 32
#define TOPG 4
#define TOPK_N 8
#define NKT 224          // DIM/32 k-tiles total
#define KSPLIT 8
#define KTS 28           // NKT/KSPLIT
#define KSLICE 896       // DIM/KSPLIT
#define BM 128

typedef short bf16x8 __attribute__((ext_vector_type(8)));
typedef float f32x4 __attribute__((ext_vector_type(4)));

#define DREL 4e-5

__device__ __forceinline__ unsigned short bf16_rne(float f) {
    unsigned u = __float_as_uint(f);
    unsigned r = u + 0x7FFFu + ((u >> 16) & 1u);
    return (unsigned short)(r >> 16);
}
__device__ __forceinline__ float bf16_to_f32(unsigned short h) {
    return __uint_as_float(((unsigned)h) << 16);
}

// ---------------- K0: repack W into fragment-major bf16 hi/lo ----------------
// frag id gid = (ct*NKT + kt)*64 + l ; element j: w[ct*16+(l&15)][kt*32+(l>>4)*8+j]
__global__ void k0_repack(const float* __restrict__ w,
                          unsigned short* __restrict__ wh,
                          unsigned short* __restrict__ wl) {
    const int gid = blockIdx.x * 256 + threadIdx.x;
    if (gid >= 16 * NKT * 64) return;
    const int l  = gid & 63;
    const int kt = (gid >> 6) % NKT;
    const int ct = gid / (NKT * 64);
    const int e  = ct * 16 + (l & 15);
    const int k0 = kt * 32 + (l >> 4) * 8;
    const float* src = w + (size_t)e * DIM + k0;
    float4 u0 = *(const float4*)src;
    float4 u1 = *(const float4*)(src + 4);
    const float uu[8] = {u0.x, u0.y, u0.z, u0.w, u1.x, u1.y, u1.z, u1.w};
    ushort4 ho[2], lo[2];
    unsigned short* hp = (unsigned short*)ho;
    unsigned short* lp = (unsigned short*)lo;
#pragma unroll
    for (int q = 0; q < 8; ++q) {
        unsigned short hb = bf16_rne(uu[q]);
        float hf = bf16_to_f32(hb);
        unsigned short lb = bf16_rne(uu[q] - hf);
        hp[q] = hb; lp[q] = lb;
    }
    *(ushort4*)(wh + (size_t)gid * 8)     = ho[0];
    *(ushort4*)(wh + (size_t)gid * 8 + 4) = ho[1];
    *(ushort4*)(wl + (size_t)gid * 8)     = lo[0];
    *(ushort4*)(wl + (size_t)gid * 8 + 4) = lo[1];
}

// ---------------- K1: fragment-direct 3-term split-bf16 GEMM ----------------
// grid = (np/BM)*KSPLIT; ks = blockIdx&7 (== XCD under round-robin dispatch);
// 512 thr, 8 waves; wave: rt pair = 2*(wv&3), ct half = 8*(wv>>2).
// B-fragments loaded transiently per-ci (keeps VGPR ~110, no spill).
__global__ __launch_bounds__(512, 2) void k1_gemm(
    const float* __restrict__ x,
    const unsigned short* __restrict__ wh, const unsigned short* __restrict__ wl,
    float* __restrict__ part, int n, int np)
{
    const int t  = threadIdx.x;
    const int l  = t & 63;
    const int wv = t >> 6;
    const int ks = blockIdx.x & 7;
    const int rb = blockIdx.x >> 3;
    const int rtb = 2 * (wv & 3);
    const int ctb = 8 * (wv >> 2);
    const int mrow  = l & 15;
    const int kslot = l >> 4;

    f32x4 acc[2][8];
#pragma unroll
    for (int rr = 0; rr < 2; ++rr)
#pragma unroll
        for (int ci = 0; ci < 8; ++ci) acc[rr][ci] = (f32x4){0.f, 0.f, 0.f, 0.f};

    size_t xoff[2];
#pragma unroll
    for (int rr = 0; rr < 2; ++rr) {
        int row = rb * BM + (rtb + rr) * 16 + mrow;
        if (row > n - 1) row = n - 1;
        xoff[rr] = (size_t)row * DIM + (size_t)ks * KSLICE + kslot * 8;
    }
    // base for B fragments of this k-slice: frag (ct*NKT + ks*KTS + tt)
    const size_t bbase = (size_t)l * 8;

#pragma unroll 1
    for (int tt = 0; tt < KTS; ++tt) {
        bf16x8 ah[2], al[2];
#pragma unroll
        for (int rr = 0; rr < 2; ++rr) {
            const float* xp = x + xoff[rr] + (size_t)tt * 32;
            float4 u0 = *(const float4*)xp;
            float4 u1 = *(const float4*)(xp + 4);
            const float uu[8] = {u0.x, u0.y, u0.z, u0.w, u1.x, u1.y, u1.z, u1.w};
            bf16x8 hh, ll;
#pragma unroll
            for (int q = 0; q < 8; ++q) {
                const unsigned u  = __float_as_uint(uu[q]);
                const unsigned hr = (u + 0x7FFFu + ((u >> 16) & 1u)) & 0xFFFF0000u;
                const float lofv  = uu[q] - __uint_as_float(hr);
                hh[q] = (short)(hr >> 16);
                ll[q] = (short)(__float_as_uint(lofv) >> 16);
            }
            ah[rr] = hh; al[rr] = ll;
        }
#pragma unroll
        for (int ci = 0; ci < 8; ++ci) {
            const size_t fb = ((size_t)((ctb + ci) * NKT + ks * KTS + tt) * 64) * 8 + bbase;
            const bf16x8 bh = *(const bf16x8*)(wh + fb);
            const bf16x8 bl = *(const bf16x8*)(wl + fb);
#pragma unroll
            for (int rr = 0; rr < 2; ++rr) {
                acc[rr][ci] = __builtin_amdgcn_mfma_f32_16x16x32_bf16(ah[rr], bh, acc[rr][ci], 0, 0, 0);
                acc[rr][ci] = __builtin_amdgcn_mfma_f32_16x16x32_bf16(ah[rr], bl, acc[rr][ci], 0, 0, 0);
                acc[rr][ci] = __builtin_amdgcn_mfma_f32_16x16x32_bf16(al[rr], bh, acc[rr][ci], 0, 0, 0);
            }
        }
    }

    // D layout: col = lane&15 (expert), row = 4*(lane>>4)+j  (verified r7/r8)
    float* pb = part + (size_t)ks * np * NE;
#pragma unroll
    for (int rr = 0; rr < 2; ++rr)
#pragma unroll
        for (int ci = 0; ci < 8; ++ci) {
            const int rl = rb * BM + (rtb + rr) * 16 + 4 * kslot;
            const int e  = (ctb + ci) * 16 + mrow;
#pragma unroll
            for (int j = 0; j < 4; ++j)
                pb[(size_t)(rl + j) * NE + e] = acc[rr][ci][j];
        }
}

// ---------------- K1b: combine partials + certificate routing ----------------
__global__ __launch_bounds__(256) void k1b_route(
    const float* __restrict__ part, const float* __restrict__ bias,
    float* __restrict__ out, unsigned* __restrict__ counter,
    int* __restrict__ list, int n, int np, unsigned lcap)
{
    __shared__ float sc[32][NE + 2];
    const int t  = threadIdx.x;
    const int r0 = blockIdx.x * 32;
#pragma unroll 1
    for (int r = 0; r < 32; ++r) {
        const size_t off = (size_t)(r0 + r) * NE + t;
        float z = 0.f;
#pragma unroll
        for (int ks = 0; ks < KSPLIT; ++ks)
            z += part[(size_t)ks * np * NE + off];
        sc[r][t] = z;
    }
    __syncthreads();

    if (t < 32) {
        const int row = r0 + t;
        if (row < n) {
            float* srow = sc[t];
            float zmaxf = -3e38f;
            for (int e = 0; e < NE; ++e) zmaxf = fmaxf(zmaxf, srow[e]);
            double Z = 0.0;
            for (int e = 0; e < NE; ++e) {
                float p = __expf(srow[e] - zmaxf);
                srow[e] = p;
                Z += (double)p;
            }
            const double invZ = 1.0 / Z;

            bool flag = false;
            double gs[NG], dg[NG];
            for (int g = 0; g < NG; ++g) {
                double v1 = -1e300, v2 = -1e300, v3 = -1e300;
                double d1 = 0, d2 = 0, d3 = 0;
                for (int i = 0; i < GSZ; ++i) {
                    double p = (double)srow[g * GSZ + i] * invZ;
                    double v = p + (double)bias[g * GSZ + i];
                    double d = DREL * p;
                    if (v > v1)      { v3 = v2; d3 = d2; v2 = v1; d2 = d1; v1 = v; d1 = d; }
                    else if (v > v2) { v3 = v2; d3 = d2; v2 = v;  d2 = d; }
                    else if (v > v3) { v3 = v;  d3 = d; }
                }
                if (v2 - v3 <= d2 + d3) flag = true;
                gs[g] = v1 + v2; dg[g] = d1 + d2;
            }
            unsigned keep = 0;
            for (int tt = 0; tt < TOPG; ++tt) {
                double best = -1e300; int bg = 0;
                for (int g = 0; g < NG; ++g)
                    if (!((keep >> g) & 1u) && gs[g] > best) { best = gs[g]; bg = g; }
                keep |= 1u << bg;
            }
            {
                double mn = 1e300, mx = -1e300;
                for (int g = 0; g < NG; ++g) {
                    if ((keep >> g) & 1u) mn = fmin(mn, gs[g] - dg[g]);
                    else                  mx = fmax(mx, gs[g] + dg[g]);
                }
                if (mn <= mx) flag = true;
            }
            unsigned long long tk[4] = {0ull, 0ull, 0ull, 0ull};
            double pv[9], pd[9]; int pe[9];
            for (int pp = 0; pp < 9; ++pp) {
                double best = -1e300, bd = 0; int be = 0;
                for (int e = 0; e < NE; ++e) {
                    if (!((keep >> (e >> 5)) & 1u)) continue;
                    if ((tk[e >> 6] >> (e & 63)) & 1ull) continue;
                    double p = (double)srow[e] * invZ;
                    double s = p + (double)bias[e];
                    if (s > best) { best = s; bd = DREL * p; be = e; }
                }
                tk[be >> 6] |= 1ull << (be & 63);
                pv[pp] = best; pd[pp] = bd; pe[pp] = be;
            }
            for (int i = 0; i < 8; ++i)
                if (pv[i] - pv[i + 1] <= pd[i] + pd[i + 1]) flag = true;

            float* out_w = out;
            float* out_i = out + (size_t)n * TOPK_N;
            for (int pp = 0; pp < TOPK_N; ++pp) {
                out_w[(size_t)row * TOPK_N + pp] = (float)((double)srow[pe[pp]] * invZ * 2.5);
                out_i[(size_t)row * TOPK_N + pp] = (float)pe[pp];
            }
            if (flag) {
                unsigned idx = atomicAdd(counter, 1u);
                if (idx < lcap) list[idx] = row;
            }
        }
    }
}

// ---------------- K2: exact fp64 recompute, ONE row per block ----------------
// 1024 thr: expert = t&255, k-quarter q = t>>8. Blocks >= F exit immediately.
__global__ __launch_bounds__(1024, 1) void k2_exact(
    const float* __restrict__ x, const float* __restrict__ w,
    const float* __restrict__ bias, float* __restrict__ out,
    const unsigned* __restrict__ counter, const int* __restrict__ list,
    int n, unsigned lcap)
{
    __shared__ double zp[4][NE];
    __shared__ double sc[NE];
    const unsigned F = min(*counter, lcap);
    if (blockIdx.x >= F) return;
    const int row = list[blockIdx.x];
    const int t = threadIdx.x;
    const int e = t & 255;
    const int q = t >> 8;

    const float* wp = w + (size_t)e * DIM + q * 1792;
    const float* xp = x + (size_t)row * DIM + q * 1792;
    double a = 0.0;
    for (int i = 0; i < 1792; i += 4) {
        const float4 wf = *(const float4*)&wp[i];
        const float4 xf = *(const float4*)&xp[i];
        a = fma((double)xf.x, (double)wf.x, a);
        a = fma((double)xf.y, (double)wf.y, a);
        a = fma((double)xf.z, (double)wf.z, a);
        a = fma((double)xf.w, (double)wf.w, a);
    }
    zp[q][e] = a;
    __syncthreads();
    if (t < NE) sc[t] = ((zp[0][t] + zp[1][t]) + zp[2][t]) + zp[3][t];
    __syncthreads();

    if (t == 0) {
        double* srow = sc;
        double zmax = -1e300;
        for (int ee = 0; ee < NE; ++ee) zmax = fmax(zmax, srow[ee]);
        double Z = 0.0;
        for (int ee = 0; ee < NE; ++ee) {
            double p = exp(srow[ee] - zmax);
            srow[ee] = p;
            Z += p;
        }
        const double invZ = 1.0 / Z;
        double gs[NG];
        for (int g = 0; g < NG; ++g) {
            double m1 = -1e300, m2 = -1e300;
            for (int i = 0; i < GSZ; ++i) {
                double v = srow[g * GSZ + i] * invZ + (double)bias[g * GSZ + i];
                if (v > m1) { m2 = m1; m1 = v; }
                else if (v > m2) { m2 = v; }
            }
            gs[g] = m1 + m2;
        }
        unsigned keep = 0;
        for (int tt = 0; tt < TOPG; ++tt) {
            double best = -1e300; int bg = 0;
            for (int g = 0; g < NG; ++g)
                if (!((keep >> g) & 1u) && gs[g] > best) { best = gs[g]; bg = g; }
            keep |= 1u << bg;
        }
        unsigned long long tk[4] = {0ull, 0ull, 0ull, 0ull};
        float* out_w = out;
        float* out_i = out + (size_t)n * TOPK_N;
        for (int pp = 0; pp < TOPK_N; ++pp) {
            double best = -1e300; int be = 0;
            for (int ee = 0; ee < NE; ++ee) {
                if (!((keep >> (ee >> 5)) & 1u)) continue;
                if ((tk[ee >> 6] >> (ee & 63)) & 1ull) continue;
                double s = srow[ee] * invZ + (double)bias[ee];
                if (s > best) { best = s; be = ee; }
            }
            tk[be >> 6] |= 1ull << (be & 63);
            out_w[(size_t)row * TOPK_N + pp] = (float)(srow[be] * invZ * 2.5);
            out_i[(size_t)row * TOPK_N + pp] = (float)be;
        }
    }
}

// ---------------- fallback (proven r6 fp64 kernel) if ws too small ----------------
#define OBM 32
#define OBK 16
#define ONCH (DIM / OBK)
__global__ __launch_bounds__(512) void gate_kernel_old(
    const float* __restrict__ x, const float* __restrict__ w,
    const float* __restrict__ bias, float* __restrict__ out, int n)
{
    __shared__ __align__(16) char smem[65536];
    float  (*w2)[OBK][NE] = reinterpret_cast<float(*)[OBK][NE]>(smem);
    double (*x2)[OBK][34] = reinterpret_cast<double(*)[OBK][34]>(smem + 32768);
    double (*sc)[OBM]     = reinterpret_cast<double(*)[OBM]>(smem);
    const int t = threadIdx.x;
    const int row0 = blockIdx.x * OBM;
    const int we = t & 255;
    const int h8 = (t >> 8) * 8;
    const size_t wbase = (size_t)we * DIM + h8;
    const int rx = t >> 2;
    const int kx = (t & 3) * 4;
    int rr = row0 + rx; if (rr > n - 1) rr = n - 1;
    const size_t xbase = (size_t)rr * DIM + kx;
    const int wv = t >> 6, lane = t & 63;
    const int h = wv & 1, rg = wv >> 1, rb = 8 * rg;
    const int e0 = 128 * h + 2 * lane;
    double acc[8][2];
#pragma unroll
    for (int i = 0; i < 8; ++i) { acc[i][0] = 0.0; acc[i][1] = 0.0; }
    float4 wra = *(const float4*)&w[wbase];
    float4 wrb = *(const float4*)&w[wbase + 4];
    float4 xr = make_float4(0.f, 0.f, 0.f, 0.f);
    if (t < 128) xr = *(const float4*)&x[xbase];
    for (int c = 0; c < ONCH; ++c) {
        const int b = c & 1;
        const float* fa = (const float*)&wra;
        const float* fb = (const float*)&wrb;
#pragma unroll
        for (int q = 0; q < 4; ++q) {
            w2[b][h8 + q][we] = fa[q];
            w2[b][h8 + 4 + q][we] = fb[q];
        }
        if (t < 128) {
            const float* fx = (const float*)&xr;
#pragma unroll
            for (int q = 0; q < 4; ++q) x2[b][kx + q][rx] = (double)fx[q];
        }
        const size_t k0 = (size_t)((c + 1 < ONCH) ? c + 1 : c) * OBK;
        wra = *(const float4*)&w[wbase + k0];
        wrb = *(const float4*)&w[wbase + k0 + 4];
        if (t < 128) xr = *(const float4*)&x[xbase + k0];
        __syncthreads();
#pragma unroll
        for (int kk = 0; kk < OBK; ++kk) {
            const float2 wf = *(const float2*)&w2[b][kk][e0];
            const double wd0 = (double)wf.x, wd1 = (double)wf.y;
            const double2 xp0 = *(const double2*)&x2[b][kk][rb];
            const double2 xp1 = *(const double2*)&x2[b][kk][rb + 2];
            const double2 xp2 = *(const double2*)&x2[b][kk][rb + 4];
            const double2 xp3 = *(const double2*)&x2[b][kk][rb + 6];
            const double xv[8] = {xp0.x, xp0.y, xp1.x, xp1.y, xp2.x, xp2.y, xp3.x, xp3.y};
#pragma unroll
            for (int i = 0; i < 8; ++i) {
                acc[i][0] = fma(xv[i], wd0, acc[i][0]);
                acc[i][1] = fma(xv[i], wd1, acc[i][1]);
            }
        }
    }
    __syncthreads();
#pragma unroll
    for (int j = 0; j < 2; ++j)
#pragma unroll
        for (int q = 0; q < 4; ++q) {
            double2 v; v.x = acc[2 * q][j]; v.y = acc[2 * q + 1][j];
            *(double2*)&sc[e0 + j][rb + 2 * q] = v;
        }
    __syncthreads();
    if (t < OBM) {
        const int row = row0 + t;
        if (row < n) {
            double zmax = -1e300;
            for (int e = 0; e < NE; ++e) zmax = fmax(zmax, sc[e][t]);
            double Z = 0.0;
            for (int e = 0; e < NE; ++e) { double p = exp(sc[e][t] - zmax); sc[e][t] = p; Z += p; }
            const double invZ = 1.0 / Z;
            double gs[NG];
            for (int g = 0; g < NG; ++g) {
                double m1 = -1e300, m2 = -1e300;
                for (int i = 0; i < GSZ; ++i) {
                    double v = sc[g * GSZ + i][t] * invZ + (double)bias[g * GSZ + i];
                    if (v > m1) { m2 = m1; m1 = v; } else if (v > m2) m2 = v;
                }
                gs[g] = m1 + m2;
            }
            unsigned keep = 0;
            for (int tt = 0; tt < TOPG; ++tt) {
                double best = -1e300; int bg = 0;
                for (int g = 0; g < NG; ++g)
                    if (!((keep >> g) & 1u) && gs[g] > best) { best = gs[g]; bg = g; }
                keep |= 1u << bg;
            }
            unsigned long long tk[4] = {0ull, 0ull, 0ull, 0ull};
            float* out_w = out;
            float* out_i = out + (size_t)n * TOPK_N;
            for (int pp = 0; pp < TOPK_N; ++pp) {
                double best = -1e300; int be = 0;
                for (int e = 0; e < NE; ++e) {
                    if (!((keep >> (e >> 5)) & 1u)) continue;
                    if ((tk[e >> 6] >> (e & 63)) & 1ull) continue;
                    double s = sc[e][t] * invZ + (double)bias[e];
                    if (s > best) { best = s; be = e; }
                }
                tk[be >> 6] |= 1ull << (be & 63);
                out_w[(size_t)row * TOPK_N + pp] = (float)(sc[be][t] * invZ * 2.5);
                out_i[(size_t)row * TOPK_N + pp] = (float)be;
            }
        }
    }
}

extern "C" void kernel_launch(void* const* d_in, const int* in_sizes, int n_in,
                              void* d_out, int out_size, void* d_ws, size_t ws_size,
                              hipStream_t stream) {
    const float* x  = (const float*)d_in[0];
    const float* w  = (const float*)d_in[1];
    const float* b  = (const float*)d_in[2];
    float* out      = (float*)d_out;
    const int n     = in_sizes[0] / DIM;
    const int np    = (n + BM - 1) & ~(BM - 1);
    const int nrb   = np / BM;

    const size_t WBYTES   = (size_t)16 * NKT * 64 * 8 * 2;  // 3,670,016 per array
    const size_t off_list = 4096;
    const size_t off_wh   = off_list + (((size_t)np * 4 + 255) & ~(size_t)255);
    const size_t off_wl   = off_wh + WBYTES;
    const size_t off_part = off_wl + WBYTES;
    const size_t need     = off_part + (size_t)KSPLIT * np * NE * 4;

    if (ws_size < need) {
        gate_kernel_old<<<(n + OBM - 1) / OBM, 512, 0, stream>>>(x, w, b, out, n);
        return;
    }
    char* ws = (char*)d_ws;
    unsigned* flagctr   = (unsigned*)ws;
    int* list           = (int*)(ws + off_list);
    unsigned short* wh  = (unsigned short*)(ws + off_wh);
    unsigned short* wl  = (unsigned short*)(ws + off_wl);
    float* part         = (float*)(ws + off_part);

    hipMemsetAsync(ws, 0, 64, stream);
    k0_repack<<<(16 * NKT * 64) / 256, 256, 0, stream>>>(w, wh, wl);
    k1_gemm<<<nrb * KSPLIT, 512, 0, stream>>>(x, wh, wl, part, n, np);
    k1b_route<<<np / 32, 256, 0, stream>>>(part, b, out, flagctr, list, n, np, (unsigned)np);
    k2_exact<<<2048, 1024, 0, stream>>>(x, w, b, out, flagctr, list, n, (unsigned)np);
}